// Round 7
// baseline (244.864 us; speedup 1.0000x reference)
//
#include <hip/hip_runtime.h>

#define NT 256
#define EPT 4
#define BLK_ELEMS (NT * EPT)            // 1024 elements per block
#define PASS_ELEMS 256                  // elements per pass (== NT)
#define NPASS (BLK_ELEMS / PASS_ELEMS)  // 4
#define ELEM_B 80                       // bytes per element (20 floats)

// K1: per-block (1024-element) sum of seq_lengths.
__global__ __launch_bounds__(NT) void tile_sum_kernel(const int* __restrict__ seq,
                                                      unsigned* __restrict__ blockTotal,
                                                      int n) {
    __shared__ unsigned wsum[4];
    const int tid = threadIdx.x, lane = tid & 63, wave = tid >> 6;
    const int base = blockIdx.x * BLK_ELEMS + tid * EPT;
    unsigned v = 0;
    if (base + EPT <= n) {
        int4 q = *(const int4*)(seq + base);
        v = (unsigned)(q.x + q.y + q.z + q.w);
    } else {
        for (int e = 0; e < EPT; e++)
            if (base + e < n) v += (unsigned)seq[base + e];
    }
    #pragma unroll
    for (int off = 32; off > 0; off >>= 1) v += __shfl_down(v, off);
    if (lane == 0) wsum[wave] = v;
    __syncthreads();
    if (tid == 0) blockTotal[blockIdx.x] = wsum[0] + wsum[1] + wsum[2] + wsum[3];
}

// K2: coalesced chunk staging (reg -> LDS, T14 split), per-element LDS reads,
// compute, LDS-compacted coalesced output. Redundant L2 prefix, no atomics.
__global__ __launch_bounds__(NT) void main_kernel(const float* __restrict__ xss,
                                                  const int* __restrict__ seq,
                                                  const float* __restrict__ Wcob,
                                                  const float* __restrict__ Wreg,
                                                  const unsigned* __restrict__ blockTotal,
                                                  float* __restrict__ out,
                                                  int n) {
    __shared__ float4   inbuf[PASS_ELEMS * 5];   // 20 KB: one pass's xss tile
    __shared__ unsigned offs[BLK_ELEMS + 1];     // packed (block-local off << 3) | L
    __shared__ float    outbuf[PASS_ELEMS * 4];  // 4 KB: one pass's compacted output
    __shared__ unsigned wred[4];                 // prefix-reduce partials
    __shared__ unsigned wtot[4];                 // scan wave totals

    const int tid = threadIdx.x, lane = tid & 63, wave = tid >> 6;
    const int bid = blockIdx.x;
    const int base = bid * BLK_ELEMS + tid * EPT;

    // ---- seq values (int4 fast path) ----
    int l[EPT];
    if (base + EPT <= n) {
        int4 q = *(const int4*)(seq + base);
        l[0] = q.x; l[1] = q.y; l[2] = q.z; l[3] = q.w;
    } else {
        #pragma unroll
        for (int e = 0; e < EPT; e++) l[e] = (base + e < n) ? seq[base + e] : 0;
    }
    const unsigned tsum = (unsigned)(l[0] + l[1] + l[2] + l[3]);

    // ---- coalesced staging addresses: lane i fetches 16B chunk (j*NT + tid)
    //      of the pass tile -> consecutive lanes, consecutive 16B. ----
    const char* xb = (const char*)xss;
    const size_t blk_byte = (size_t)bid * BLK_ELEMS * ELEM_B;
    const size_t limit = (size_t)n * ELEM_B - 16;   // last valid 16B chunk
    auto stage_addr = [&](int p, int j) -> const float4* {
        size_t a = blk_byte + (size_t)p * (PASS_ELEMS * ELEM_B) + (size_t)(j * NT + tid) * 16;
        if (a > limit) a = limit;                   // tail clamp (data unused: L=0)
        return (const float4*)(xb + a);
    };
    // prologue: pass-0 loads in flight under the scan below
    float4 r0 = *stage_addr(0, 0), r1 = *stage_addr(0, 1), r2 = *stage_addr(0, 2),
           r3 = *stage_addr(0, 3), r4 = *stage_addr(0, 4);

    // ---- global prefix: reduce blockTotal[0..bid) (L2-broadcast) ----
    unsigned acc = 0;
    for (int i = tid; i < bid; i += NT) acc += blockTotal[i];
    unsigned r = acc;
    #pragma unroll
    for (int off = 32; off > 0; off >>= 1) r += __shfl_down(r, off);
    if (lane == 0) wred[wave] = r;

    // ---- block-wide exclusive scan over thread sums ----
    unsigned v = tsum;
    #pragma unroll
    for (int off = 1; off < 64; off <<= 1) {
        unsigned t = __shfl_up(v, off);
        if (lane >= off) v += t;
    }
    if (lane == 63) wtot[wave] = v;
    __syncthreads();
    const unsigned prefix = wred[0] + wred[1] + wred[2] + wred[3];
    unsigned woff = 0;
    #pragma unroll
    for (int w = 0; w < 4; w++) woff += (w < wave) ? wtot[w] : 0u;

    // ---- publish per-element block-local offsets (+L) to LDS ----
    unsigned run = woff + (v - tsum);
    #pragma unroll
    for (int e = 0; e < EPT; e++) {
        offs[tid * EPT + e] = (run << 3) | (unsigned)l[e];
        run += (unsigned)l[e];
    }
    if (tid == NT - 1) offs[BLK_ELEMS] = run << 3;   // block total sentinel

    // ---- uniform weights (scalarized) ----
    float wc[16], wr[16];
    #pragma unroll
    for (int i = 0; i < 16; i++) { wc[i] = Wcob[i]; wr[i] = Wreg[i]; }

    // ---- pass loop: stage -> compute -> copy out ----
    for (int p = 0; p < NPASS; ++p) {
        __syncthreads();   // inbuf free, outbuf copied (p>0), offs visible (p==0)
        inbuf[0 * NT + tid] = r0;
        inbuf[1 * NT + tid] = r1;
        inbuf[2 * NT + tid] = r2;
        inbuf[3 * NT + tid] = r3;
        inbuf[4 * NT + tid] = r4;
        if (p + 1 < NPASS) {     // issue next pass's loads: fly under compute
            r0 = *stage_addr(p + 1, 0);
            r1 = *stage_addr(p + 1, 1);
            r2 = *stage_addr(p + 1, 2);
            r3 = *stage_addr(p + 1, 3);
            r4 = *stage_addr(p + 1, 4);
        }
        __syncthreads();   // inbuf ready

        const unsigned pk = offs[p * PASS_ELEMS + tid];
        const unsigned pb = offs[p * PASS_ELEMS] >> 3;        // pass base (block-local)
        const unsigned pe = offs[(p + 1) * PASS_ELEMS] >> 3;  // next base
        const int L = (int)(pk & 7u);
        const unsigned oo = (pk >> 3) - pb;                   // outbuf slot

        // element's 80B from LDS: stride 20 words -> bank-balanced per 1/4-wave
        const float4* ep = inbuf + tid * 5;
        float4 A = ep[0], Bq = ep[1], C = ep[2], D = ep[3], E = ep[4];
        float x[20];
        x[0]=A.x;  x[1]=A.y;  x[2]=A.z;  x[3]=A.w;
        x[4]=Bq.x; x[5]=Bq.y; x[6]=Bq.z; x[7]=Bq.w;
        x[8]=C.x;  x[9]=C.y;  x[10]=C.z; x[11]=C.w;
        x[12]=D.x; x[13]=D.y; x[14]=D.z; x[15]=D.w;
        x[16]=E.x; x[17]=E.y; x[18]=E.z; x[19]=E.w;

        // bs[s][c] = sum_f fs[s][f] * Wcob[c][f]
        float bs[4][4];
        #pragma unroll
        for (int s = 0; s < 4; s++) {
            #pragma unroll
            for (int c = 0; c < 4; c++) {
                float a = 0.f;
                #pragma unroll
                for (int f = 0; f < 4; f++) a += x[s * 5 + 1 + f] * wc[c * 4 + f];
                bs[s][c] = a;
            }
        }
        // context[c] = sum_{s<L} bs[s][c] * scale[s]
        float ctx[4] = {0.f, 0.f, 0.f, 0.f};
        #pragma unroll
        for (int s = 0; s < 4; s++) {
            float m = (s < L) ? x[s * 5] : 0.f;
            #pragma unroll
            for (int c = 0; c < 4; c++) ctx[c] += bs[s][c] * m;
        }
        // ys[m] = sum_c ctx[c] * Wreg[m][c]
        float ys[4];
        #pragma unroll
        for (int m = 0; m < 4; m++) {
            float a = 0.f;
            #pragma unroll
            for (int c = 0; c < 4; c++) a += ctx[c] * wr[m * 4 + c];
            ys[m] = a;
        }
        // projs[s] -> compacted into outbuf
        #pragma unroll
        for (int s = 0; s < 4; s++) {
            if (s < L) {
                float a = 0.f;
                #pragma unroll
                for (int m = 0; m < 4; m++) a += bs[s][m] * ys[m];
                outbuf[oo + s] = a;
            }
        }

        __syncthreads();   // outbuf ready
        const unsigned tp = pe - pb;
        for (unsigned i = tid; i < tp; i += NT)
            out[prefix + pb + i] = outbuf[i];
        // loop-top barrier protects outbuf/inbuf reuse
    }
}

extern "C" void kernel_launch(void* const* d_in, const int* in_sizes, int n_in,
                              void* d_out, int out_size, void* d_ws, size_t ws_size,
                              hipStream_t stream) {
    const float* xss  = (const float*)d_in[0];
    const int*   seq  = (const int*)d_in[1];
    const float* Wcob = (const float*)d_in[2];
    const float* Wreg = (const float*)d_in[3];
    float* out = (float*)d_out;

    int n  = in_sizes[1];                       // B = 2,000,000
    int nb = (n + BLK_ELEMS - 1) / BLK_ELEMS;   // 1954 blocks

    unsigned* blockTotal = (unsigned*)d_ws;     // nb words; fully overwritten by K1

    tile_sum_kernel<<<nb, NT, 0, stream>>>(seq, blockTotal, n);
    main_kernel<<<nb, NT, 0, stream>>>(xss, seq, Wcob, Wreg, blockTotal, out, n);
}

// Round 8
// 241.806 us; speedup vs baseline: 1.0126x; 1.0126x over previous
//
#include <hip/hip_runtime.h>

#define NT 256
#define EPT 4
#define BLK_ELEMS (NT * EPT)            // 1024 elements per block
#define PASS_ELEMS 256                  // elements per pass (== NT)
#define NPASS (BLK_ELEMS / PASS_ELEMS)  // 4
#define ELEM_B 80                       // bytes per element (20 floats)

// K1: per-block (1024-element) sum of seq_lengths.
__global__ __launch_bounds__(NT) void tile_sum_kernel(const int* __restrict__ seq,
                                                      unsigned* __restrict__ blockTotal,
                                                      int n) {
    __shared__ unsigned wsum[4];
    const int tid = threadIdx.x, lane = tid & 63, wave = tid >> 6;
    const int base = blockIdx.x * BLK_ELEMS + tid * EPT;
    unsigned v = 0;
    if (base + EPT <= n) {
        int4 q = *(const int4*)(seq + base);
        v = (unsigned)(q.x + q.y + q.z + q.w);
    } else {
        for (int e = 0; e < EPT; e++)
            if (base + e < n) v += (unsigned)seq[base + e];
    }
    #pragma unroll
    for (int off = 32; off > 0; off >>= 1) v += __shfl_down(v, off);
    if (lane == 0) wsum[wave] = v;
    __syncthreads();
    if (tid == 0) blockTotal[blockIdx.x] = wsum[0] + wsum[1] + wsum[2] + wsum[3];
}

// K2: round-7 structure + 2-deep register prefetch. Two named register sets
// (a*, b*) alternate across passes; pass p+2's loads are issued during pass
// p's write phase, so the ds_write's counted vmcnt wait always has ~1.5
// iterations of cover and each wave sustains ~10KB in flight.
__global__ __launch_bounds__(NT) void main_kernel(const float* __restrict__ xss,
                                                  const int* __restrict__ seq,
                                                  const float* __restrict__ Wcob,
                                                  const float* __restrict__ Wreg,
                                                  const unsigned* __restrict__ blockTotal,
                                                  float* __restrict__ out,
                                                  int n) {
    __shared__ float4   inbuf[PASS_ELEMS * 5];   // 20 KB: one pass's xss tile
    __shared__ unsigned offs[BLK_ELEMS + 1];     // packed (block-local off << 3) | L
    __shared__ float    outbuf[PASS_ELEMS * 4];  // 4 KB: one pass's compacted output
    __shared__ unsigned wred[4];                 // prefix-reduce partials
    __shared__ unsigned wtot[4];                 // scan wave totals

    const int tid = threadIdx.x, lane = tid & 63, wave = tid >> 6;
    const int bid = blockIdx.x;
    const int base = bid * BLK_ELEMS + tid * EPT;

    // ---- seq values (int4 fast path) ----
    int l[EPT];
    if (base + EPT <= n) {
        int4 q = *(const int4*)(seq + base);
        l[0] = q.x; l[1] = q.y; l[2] = q.z; l[3] = q.w;
    } else {
        #pragma unroll
        for (int e = 0; e < EPT; e++) l[e] = (base + e < n) ? seq[base + e] : 0;
    }
    const unsigned tsum = (unsigned)(l[0] + l[1] + l[2] + l[3]);

    // ---- coalesced staging addresses: lane i fetches 16B chunk (j*NT + tid)
    //      of the pass tile -> consecutive lanes, consecutive 16B. ----
    const char* xb = (const char*)xss;
    const size_t blk_byte = (size_t)bid * BLK_ELEMS * ELEM_B;
    const size_t limit = (size_t)n * ELEM_B - 16;   // last valid 16B chunk
    auto stage_addr = [&](int p, int j) -> const float4* {
        size_t a = blk_byte + (size_t)p * (PASS_ELEMS * ELEM_B) + (size_t)(j * NT + tid) * 16;
        if (a > limit) a = limit;                   // tail clamp (data unused: L=0)
        return (const float4*)(xb + a);
    };
    // prologue: TWO passes' loads in flight under the scan below (10 x 16B/thread)
    float4 a0 = *stage_addr(0, 0), a1 = *stage_addr(0, 1), a2 = *stage_addr(0, 2),
           a3 = *stage_addr(0, 3), a4 = *stage_addr(0, 4);
    float4 b0 = *stage_addr(1, 0), b1 = *stage_addr(1, 1), b2 = *stage_addr(1, 2),
           b3 = *stage_addr(1, 3), b4 = *stage_addr(1, 4);

    // ---- global prefix: reduce blockTotal[0..bid) (L2-broadcast) ----
    unsigned acc = 0;
    for (int i = tid; i < bid; i += NT) acc += blockTotal[i];
    unsigned r = acc;
    #pragma unroll
    for (int off = 32; off > 0; off >>= 1) r += __shfl_down(r, off);
    if (lane == 0) wred[wave] = r;

    // ---- block-wide exclusive scan over thread sums ----
    unsigned v = tsum;
    #pragma unroll
    for (int off = 1; off < 64; off <<= 1) {
        unsigned t = __shfl_up(v, off);
        if (lane >= off) v += t;
    }
    if (lane == 63) wtot[wave] = v;
    __syncthreads();
    const unsigned prefix = wred[0] + wred[1] + wred[2] + wred[3];
    unsigned woff = 0;
    #pragma unroll
    for (int w = 0; w < 4; w++) woff += (w < wave) ? wtot[w] : 0u;

    // ---- publish per-element block-local offsets (+L) to LDS ----
    unsigned run = woff + (v - tsum);
    #pragma unroll
    for (int e = 0; e < EPT; e++) {
        offs[tid * EPT + e] = (run << 3) | (unsigned)l[e];
        run += (unsigned)l[e];
    }
    if (tid == NT - 1) offs[BLK_ELEMS] = run << 3;   // block total sentinel

    // ---- uniform weights (scalarized) ----
    float wc[16], wr[16];
    #pragma unroll
    for (int i = 0; i < 16; i++) { wc[i] = Wcob[i]; wr[i] = Wreg[i]; }

    // ---- pass loop (fully unrolled: (p&1) register-set choice is static) ----
    #pragma unroll
    for (int p = 0; p < NPASS; ++p) {
        __syncthreads();   // inbuf free, outbuf copied (p>0), offs visible (p==0)
        if ((p & 1) == 0) {
            // counted wait: only a0..a4 drain; b-set's 5 loads stay in flight
            inbuf[0 * NT + tid] = a0;
            inbuf[1 * NT + tid] = a1;
            inbuf[2 * NT + tid] = a2;
            inbuf[3 * NT + tid] = a3;
            inbuf[4 * NT + tid] = a4;
            if (p + 2 < NPASS) {           // refill set A for pass p+2
                a0 = *stage_addr(p + 2, 0);
                a1 = *stage_addr(p + 2, 1);
                a2 = *stage_addr(p + 2, 2);
                a3 = *stage_addr(p + 2, 3);
                a4 = *stage_addr(p + 2, 4);
            }
        } else {
            inbuf[0 * NT + tid] = b0;
            inbuf[1 * NT + tid] = b1;
            inbuf[2 * NT + tid] = b2;
            inbuf[3 * NT + tid] = b3;
            inbuf[4 * NT + tid] = b4;
            if (p + 2 < NPASS) {           // refill set B for pass p+2
                b0 = *stage_addr(p + 2, 0);
                b1 = *stage_addr(p + 2, 1);
                b2 = *stage_addr(p + 2, 2);
                b3 = *stage_addr(p + 2, 3);
                b4 = *stage_addr(p + 2, 4);
            }
        }
        __syncthreads();   // inbuf ready

        const unsigned pk = offs[p * PASS_ELEMS + tid];
        const unsigned pb = offs[p * PASS_ELEMS] >> 3;        // pass base (block-local)
        const unsigned pe = offs[(p + 1) * PASS_ELEMS] >> 3;  // next base
        const int L = (int)(pk & 7u);
        const unsigned oo = (pk >> 3) - pb;                   // outbuf slot

        // element's 80B from LDS: stride 20 words -> bank-balanced per 1/4-wave
        const float4* ep = inbuf + tid * 5;
        float4 A = ep[0], Bq = ep[1], C = ep[2], D = ep[3], E = ep[4];
        float x[20];
        x[0]=A.x;  x[1]=A.y;  x[2]=A.z;  x[3]=A.w;
        x[4]=Bq.x; x[5]=Bq.y; x[6]=Bq.z; x[7]=Bq.w;
        x[8]=C.x;  x[9]=C.y;  x[10]=C.z; x[11]=C.w;
        x[12]=D.x; x[13]=D.y; x[14]=D.z; x[15]=D.w;
        x[16]=E.x; x[17]=E.y; x[18]=E.z; x[19]=E.w;

        // bs[s][c] = sum_f fs[s][f] * Wcob[c][f]
        float bs[4][4];
        #pragma unroll
        for (int s = 0; s < 4; s++) {
            #pragma unroll
            for (int c = 0; c < 4; c++) {
                float a = 0.f;
                #pragma unroll
                for (int f = 0; f < 4; f++) a += x[s * 5 + 1 + f] * wc[c * 4 + f];
                bs[s][c] = a;
            }
        }
        // context[c] = sum_{s<L} bs[s][c] * scale[s]
        float ctx[4] = {0.f, 0.f, 0.f, 0.f};
        #pragma unroll
        for (int s = 0; s < 4; s++) {
            float m = (s < L) ? x[s * 5] : 0.f;
            #pragma unroll
            for (int c = 0; c < 4; c++) ctx[c] += bs[s][c] * m;
        }
        // ys[m] = sum_c ctx[c] * Wreg[m][c]
        float ys[4];
        #pragma unroll
        for (int m = 0; m < 4; m++) {
            float a = 0.f;
            #pragma unroll
            for (int c = 0; c < 4; c++) a += ctx[c] * wr[m * 4 + c];
            ys[m] = a;
        }
        // projs[s] -> compacted into outbuf
        #pragma unroll
        for (int s = 0; s < 4; s++) {
            if (s < L) {
                float a = 0.f;
                #pragma unroll
                for (int m = 0; m < 4; m++) a += bs[s][m] * ys[m];
                outbuf[oo + s] = a;
            }
        }

        __syncthreads();   // outbuf ready
        const unsigned tp = pe - pb;
        for (unsigned i = tid; i < tp; i += NT)
            out[prefix + pb + i] = outbuf[i];
        // loop-top barrier protects outbuf/inbuf reuse
    }
}

extern "C" void kernel_launch(void* const* d_in, const int* in_sizes, int n_in,
                              void* d_out, int out_size, void* d_ws, size_t ws_size,
                              hipStream_t stream) {
    const float* xss  = (const float*)d_in[0];
    const int*   seq  = (const int*)d_in[1];
    const float* Wcob = (const float*)d_in[2];
    const float* Wreg = (const float*)d_in[3];
    float* out = (float*)d_out;

    int n  = in_sizes[1];                       // B = 2,000,000
    int nb = (n + BLK_ELEMS - 1) / BLK_ELEMS;   // 1954 blocks

    unsigned* blockTotal = (unsigned*)d_ws;     // nb words; fully overwritten by K1

    tile_sum_kernel<<<nb, NT, 0, stream>>>(seq, blockTotal, n);
    main_kernel<<<nb, NT, 0, stream>>>(xss, seq, Wcob, Wreg, blockTotal, out, n);
}